// Round 5
// baseline (200.169 us; speedup 1.0000x reference)
//
#include <hip/hip_runtime.h>

#define NA 4
#define NH 3
#define NHI 2
#define Bsz 32768
#define Ssz 256
#define Csz 16
#define Dsz 128
#define INsz 176
#define NP 20
#define KP 192

typedef __bf16 v8bf __attribute__((ext_vector_type(8)));
typedef float v4f __attribute__((ext_vector_type(4)));

// ---- ws layout (bytes) ----
#define OFF_ENC    0                    // Bsz*Dsz*2          = 8388608
#define OFF_ACSBF  8388608              // NA*NH*Bsz*Csz*2    = 12582912
#define OFF_W1F    20971520             // NP*6*8*512*2       = 983040  (fragment-order)
#define OFF_ENCWF  21954560             // 8*8*512*2          = 65536   (fragment-order)
#define OFF_W2T    22020096             // NP*Csz*Dsz*2       = 81920
#define OFF_AMX    22102016             // NA*NH*Bsz          = 393216
#define OFF_ZERO   22495232             // 64 B zeros

// ---- prep ranges ----
#define N_ACSROW (NA*NH*Bsz)            // 393216: one acs row -> bf16 + argmax
#define N_W1F   (NP*192*32)             // 122880
#define N_ENCWF (256*32)                // 8192
#define N_W2T   (NP*Csz*Dsz)            // 40960
#define N_ZERO  16
#define N_PREP  (N_ACSROW+N_W1F+N_ENCWF+N_W2T+N_ZERO)

__global__ __launch_bounds__(256) void prep_kernel(
    const float* __restrict__ acs, const float* __restrict__ encW,
    const float* __restrict__ eW1, const float* __restrict__ iW1,
    const float* __restrict__ eW2, const float* __restrict__ iW2,
    char* __restrict__ ws)
{
    long tid = (long)blockIdx.x * 256 + threadIdx.x;

    if (tid < N_ACSROW) {          // acs row: fp32->bf16 convert + first-max argmax, coalesced
        const float4* src = (const float4*)(acs + (size_t)tid * 16);
        float4 f0 = src[0], f1 = src[1], f2 = src[2], f3 = src[3];
        float v[16] = {f0.x,f0.y,f0.z,f0.w, f1.x,f1.y,f1.z,f1.w,
                       f2.x,f2.y,f2.z,f2.w, f3.x,f3.y,f3.z,f3.w};
        v8bf o0, o1;
        #pragma unroll
        for (int i = 0; i < 8; ++i) { o0[i] = (__bf16)v[i]; o1[i] = (__bf16)v[8 + i]; }
        v8bf* dst = (v8bf*)(ws + OFF_ACSBF) + tid * 2;
        dst[0] = o0; dst[1] = o1;
        float best = v[0]; int bi = 0;
        #pragma unroll
        for (int c = 1; c < 16; ++c) if (v[c] > best) { best = v[c]; bi = c; }
        ((unsigned char*)(ws + OFF_AMX))[tid] = (unsigned char)bi;
        return;
    }
    tid -= N_ACSROW;
    if (tid < N_W1F) {             // W1 -> bf16 fragment-order [p][kc][nt][lane][8]
        const int n4 = (int)(tid & 31) * 4;
        const int k  = (int)((tid >> 5) % 192);
        const int p  = (int)(tid / 6144);
        const float* W1;
        if (p < 12) { int ai = p / 3, hj = p % 3; W1 = eW1 + (size_t)(hj * NA + ai) * INsz * Dsz; }
        else { int qq = p - 12; int ai = qq >> 1, jj = qq & 1; W1 = iW1 + (size_t)(jj * NA + ai) * INsz * Dsz; }
        float4 f = (k < INsz) ? *(const float4*)(W1 + (size_t)k * Dsz + n4)
                              : (float4){0.f, 0.f, 0.f, 0.f};
        const int kc = k >> 5, q = (k >> 3) & 3, j = k & 7;
        __bf16* dst = (__bf16*)(ws + OFF_W1F);
        const float fv[4] = {f.x, f.y, f.z, f.w};
        #pragma unroll
        for (int i = 0; i < 4; ++i) {
            const int n = n4 + i, nt = n >> 4, m = n & 15;
            dst[((size_t)(p * 6 + kc) * 8 + nt) * 512 + (q * 16 + m) * 8 + j] = (__bf16)fv[i];
        }
        return;
    }
    tid -= N_W1F;
    if (tid < N_ENCWF) {           // encW -> bf16 fragment-order [kc][nt][lane][8]
        const int n4 = (int)(tid & 31) * 4;
        const int k  = (int)(tid >> 5);
        float4 f = *(const float4*)(encW + (size_t)k * Dsz + n4);
        const int kc = k >> 5, q = (k >> 3) & 3, j = k & 7;
        __bf16* dst = (__bf16*)(ws + OFF_ENCWF);
        const float fv[4] = {f.x, f.y, f.z, f.w};
        #pragma unroll
        for (int i = 0; i < 4; ++i) {
            const int n = n4 + i, nt = n >> 4, m = n & 15;
            dst[((size_t)kc * 8 + nt) * 512 + (q * 16 + m) * 8 + j] = (__bf16)fv[i];
        }
        return;
    }
    tid -= N_ENCWF;
    if (tid < N_W2T) {             // W2 -> bf16 transposed [p][c][d]
        int d = (int)(tid & 127);
        int rest = (int)(tid >> 7);
        int c = rest & 15, p = rest >> 4;
        const float* W2;
        if (p < 12) { int ai = p / 3, hj = p % 3; W2 = eW2 + (size_t)(hj * NA + ai) * Dsz * Csz; }
        else { int qq = p - 12; int ai = qq >> 1, jj = qq & 1; W2 = iW2 + (size_t)(jj * NA + ai) * Dsz * Csz; }
        ((__bf16*)(ws + OFF_W2T))[(size_t)p * Csz * Dsz + (size_t)c * Dsz + d] = (__bf16)W2[(size_t)d * Csz + c];
        return;
    }
    tid -= N_W2T;
    if (tid < N_ZERO) ((float*)(ws + OFF_ZERO))[tid] = 0.f;
}

// ---------------- encoder: wave = 16 rows x all 128 cols, coalesced B, no LDS ----------------
__global__ __launch_bounds__(256) void enc_kernel(const float* __restrict__ sv,
                                                  const float* __restrict__ encb,
                                                  char* __restrict__ ws)
{
    const int t = threadIdx.x;
    const int wv = t >> 6, lane = t & 63, m = lane & 15, q = lane >> 4;
    const int R = blockIdx.x * 64 + wv * 16 + m;
    const __bf16* encwf = (const __bf16*)(ws + OFF_ENCWF);
    __bf16* enc = (__bf16*)(ws + OFF_ENC);

    v4f acc[8];
    #pragma unroll
    for (int nt = 0; nt < 8; ++nt) acc[nt] = (v4f){0.f, 0.f, 0.f, 0.f};

    const float* arow = sv + (size_t)R * Ssz + q * 8;
    #pragma unroll
    for (int kc = 0; kc < 8; ++kc) {
        float4 f0 = *(const float4*)(arow + kc * 32);
        float4 f1 = *(const float4*)(arow + kc * 32 + 4);
        v8bf af;
        af[0]=(__bf16)f0.x; af[1]=(__bf16)f0.y; af[2]=(__bf16)f0.z; af[3]=(__bf16)f0.w;
        af[4]=(__bf16)f1.x; af[5]=(__bf16)f1.y; af[6]=(__bf16)f1.z; af[7]=(__bf16)f1.w;
        #pragma unroll
        for (int nt = 0; nt < 8; ++nt) {
            v8bf bf = *(const v8bf*)(encwf + ((size_t)kc * 8 + nt) * 512 + lane * 8);
            acc[nt] = __builtin_amdgcn_mfma_f32_16x16x32_bf16(af, bf, acc[nt], 0, 0, 0);
        }
    }
    const int rbase = blockIdx.x * 64 + wv * 16 + q * 4;
    #pragma unroll
    for (int nt = 0; nt < 8; ++nt) {
        const float bias = encb[nt * 16 + m];
        #pragma unroll
        for (int rg = 0; rg < 4; ++rg) {
            float v = acc[nt][rg] + bias;
            v = v > 0.f ? v : 0.f;
            enc[(size_t)(rbase + rg) * Dsz + nt * 16 + m] = (__bf16)v;
        }
    }
}

// ---------------- critic: wave = 32 rows x 128 cols, 3 waves/SIMD, p-inner swizzle ----------------
__global__ __launch_bounds__(256, 3) void critic_kernel(
    const float* __restrict__ eb1, const float* __restrict__ eb2,
    const float* __restrict__ ib1, const float* __restrict__ ib2,
    const char* __restrict__ ws, float* __restrict__ out)
{
    const int t = threadIdx.x;
    const int p  = blockIdx.x % 20;          // p-inner: same-row blocks dispatch-adjacent
    const int rb = blockIdx.x / 20;
    const int wv = t >> 6, lane = t & 63, m = lane & 15, q = lane >> 4;
    const int rw = rb * 128 + wv * 32;       // this wave's first row

    int ai, hj;
    const float *b1, *b2;
    float* outp;
    if (p < 12) {
        ai = p / 3; hj = p % 3;
        const int wi = hj * NA + ai;
        b1 = eb1 + (size_t)wi * Dsz; b2 = eb2 + (size_t)wi * Csz;
        outp = out + (size_t)(ai * NH + hj) * Bsz;
    } else {
        const int qq = p - 12; ai = qq >> 1; const int jj = qq & 1; hj = jj + 1;
        const int wi = jj * NA + ai;
        b1 = ib1 + (size_t)wi * Dsz; b2 = ib2 + (size_t)wi * Csz;
        outp = out + (size_t)NA * NH * Bsz + (size_t)(ai * NHI + jj) * Bsz;
    }

    const __bf16* acsb = (const __bf16*)(ws + OFF_ACSBF);
    const __bf16* encp = (const __bf16*)(ws + OFF_ENC);
    const __bf16* w1f  = (const __bf16*)(ws + OFF_W1F) + (size_t)p * 6 * 8 * 512;
    const __bf16* w2t  = (const __bf16*)(ws + OFF_W2T) + (size_t)p * Csz * Dsz;
    const unsigned char* amx = (const unsigned char*)(ws + OFF_AMX) + (size_t)(ai * NH + hj) * Bsz + rw;
    const __bf16* zerop = (const __bf16*)(ws + OFF_ZERO);

    const int loo0 = 0 + (0 >= ai), loo1 = 1 + (1 >= ai), loo2 = 2 + (2 >= ai);
    const __bf16* a0p = acsb + (size_t)(loo0 * NH + hj) * Bsz * Csz;
    const __bf16* a1p = acsb + (size_t)(loo1 * NH + hj) * Bsz * Csz;
    const __bf16* a2p = acsb + (size_t)(loo2 * NH + hj) * Bsz * Csz;

    const int R0 = rw + m;
    const __bf16* base[6];
    int strd[6];
    base[0] = (q < 2) ? (a0p + (size_t)R0 * Csz + q * 8) : (a1p + (size_t)R0 * Csz + (q - 2) * 8);
    strd[0] = Csz;
    base[1] = (q < 2) ? (a2p + (size_t)R0 * Csz + q * 8) : (encp + (size_t)R0 * Dsz + (q - 2) * 8);
    strd[1] = (q < 2) ? Csz : Dsz;
    base[2] = encp + (size_t)R0 * Dsz + 16 + q * 8;  strd[2] = Dsz;
    base[3] = encp + (size_t)R0 * Dsz + 48 + q * 8;  strd[3] = Dsz;
    base[4] = encp + (size_t)R0 * Dsz + 80 + q * 8;  strd[4] = Dsz;
    base[5] = (q < 2) ? (encp + (size_t)R0 * Dsz + 112 + q * 8) : zerop;
    strd[5] = (q < 2) ? Dsz : 0;

    v4f acc[2][8];
    #pragma unroll
    for (int i = 0; i < 2; ++i)
        #pragma unroll
        for (int j = 0; j < 8; ++j)
            acc[i][j] = (v4f){0.f, 0.f, 0.f, 0.f};

    #pragma unroll
    for (int kc = 0; kc < 6; ++kc) {
        v8bf bf[8];
        #pragma unroll
        for (int nt = 0; nt < 8; ++nt)
            bf[nt] = *(const v8bf*)(w1f + ((size_t)kc * 8 + nt) * 512 + lane * 8);
        v8bf af[2];
        #pragma unroll
        for (int mt = 0; mt < 2; ++mt)
            af[mt] = *(const v8bf*)(base[kc] + (size_t)(mt * 16) * strd[kc]);
        #pragma unroll
        for (int mt = 0; mt < 2; ++mt)
            #pragma unroll
            for (int nt = 0; nt < 8; ++nt)
                acc[mt][nt] = __builtin_amdgcn_mfma_f32_16x16x32_bf16(af[mt], bf[nt], acc[mt][nt], 0, 0, 0);
    }

    // wave-local epilogue: relu(acc+b1) . w2[:,argmax], shfl over the 16 m-lanes, direct store
    float b1v[8];
    #pragma unroll
    for (int nt = 0; nt < 8; ++nt) b1v[nt] = b1[nt * 16 + m];

    #pragma unroll
    for (int mt = 0; mt < 2; ++mt) {
        const int rowb = mt * 16 + q * 4;
        const unsigned int cw = *(const unsigned int*)(amx + rowb);
        #pragma unroll
        for (int rg = 0; rg < 4; ++rg) {
            const int c = (cw >> (8 * rg)) & 255;
            const __bf16* wc = w2t + (size_t)c * Dsz + m;
            float partial = 0.f;
            #pragma unroll
            for (int nt = 0; nt < 8; ++nt) {
                float h = acc[mt][nt][rg] + b1v[nt];
                h = h > 0.f ? h : 0.f;
                partial += h * (float)wc[nt * 16];
            }
            partial += __shfl_xor(partial, 1, 64);
            partial += __shfl_xor(partial, 2, 64);
            partial += __shfl_xor(partial, 4, 64);
            partial += __shfl_xor(partial, 8, 64);
            if (m == 0)
                outp[rw + rowb + rg] = partial + b2[c];
        }
    }
}

extern "C" void kernel_launch(void* const* d_in, const int* in_sizes, int n_in,
                              void* d_out, int out_size, void* d_ws, size_t ws_size,
                              hipStream_t stream) {
    const float* sv   = (const float*)d_in[0];
    const float* acs  = (const float*)d_in[1];
    const float* encW = (const float*)d_in[2];
    const float* encb = (const float*)d_in[3];
    const float* eW1  = (const float*)d_in[4];
    const float* eb1  = (const float*)d_in[5];
    const float* eW2  = (const float*)d_in[6];
    const float* eb2  = (const float*)d_in[7];
    const float* iW1  = (const float*)d_in[8];
    const float* ib1  = (const float*)d_in[9];
    const float* iW2  = (const float*)d_in[10];
    const float* ib2  = (const float*)d_in[11];
    float* out = (float*)d_out;
    char* ws = (char*)d_ws;

    hipLaunchKernelGGL(prep_kernel, dim3((N_PREP + 255) / 256), dim3(256), 0, stream,
                       acs, encW, eW1, iW1, eW2, iW2, ws);
    hipLaunchKernelGGL(enc_kernel, dim3(Bsz / 64), dim3(256), 0, stream, sv, encb, ws);
    hipLaunchKernelGGL(critic_kernel, dim3((Bsz / 128) * NP), dim3(256), 0, stream,
                       eb1, eb2, ib1, ib2, ws, out);
}

// Round 6
// 178.799 us; speedup vs baseline: 1.1195x; 1.1195x over previous
//
#include <hip/hip_runtime.h>

#define NA 4
#define NH 3
#define NHI 2
#define Bsz 32768
#define Ssz 256
#define Csz 16
#define Dsz 128
#define INsz 176
#define NP 20
#define KP 192

typedef __bf16 v8bf __attribute__((ext_vector_type(8)));
typedef float v4f __attribute__((ext_vector_type(4)));

// ---- ws layout (bytes) ----
#define OFF_ENC    0                    // Bsz*Dsz*2          = 8388608
#define OFF_ACSBF  8388608              // NA*NH*Bsz*Csz*2    = 12582912
#define OFF_W1F    20971520             // NP*6*8*512*2       = 983040  (fragment-order)
#define OFF_ENCWF  21954560             // 8*8*512*2          = 65536   (fragment-order)
#define OFF_W2T    22020096             // NP*Csz*Dsz*2       = 81920
#define OFF_AMX    22102016             // NA*NH*Bsz          = 393216
#define OFF_ZERO   22495232             // 64 B zeros

// ---- prep ranges ----
#define N_ACSROW (NA*NH*Bsz)            // 393216: one acs row -> bf16 + argmax
#define N_W1F   (NP*192*32)             // 122880
#define N_ENCWF (256*32)                // 8192
#define N_W2T   (NP*Csz*Dsz)            // 40960
#define N_ZERO  16
#define N_PREP  (N_ACSROW+N_W1F+N_ENCWF+N_W2T+N_ZERO)

__global__ __launch_bounds__(256) void prep_kernel(
    const float* __restrict__ acs, const float* __restrict__ encW,
    const float* __restrict__ eW1, const float* __restrict__ iW1,
    const float* __restrict__ eW2, const float* __restrict__ iW2,
    char* __restrict__ ws)
{
    long tid = (long)blockIdx.x * 256 + threadIdx.x;

    if (tid < N_ACSROW) {          // acs row: fp32->bf16 convert + first-max argmax, coalesced
        const float4* src = (const float4*)(acs + (size_t)tid * 16);
        float4 f0 = src[0], f1 = src[1], f2 = src[2], f3 = src[3];
        float v[16] = {f0.x,f0.y,f0.z,f0.w, f1.x,f1.y,f1.z,f1.w,
                       f2.x,f2.y,f2.z,f2.w, f3.x,f3.y,f3.z,f3.w};
        v8bf o0, o1;
        #pragma unroll
        for (int i = 0; i < 8; ++i) { o0[i] = (__bf16)v[i]; o1[i] = (__bf16)v[8 + i]; }
        v8bf* dst = (v8bf*)(ws + OFF_ACSBF) + tid * 2;
        dst[0] = o0; dst[1] = o1;
        float best = v[0]; int bi = 0;
        #pragma unroll
        for (int c = 1; c < 16; ++c) if (v[c] > best) { best = v[c]; bi = c; }
        ((unsigned char*)(ws + OFF_AMX))[tid] = (unsigned char)bi;
        return;
    }
    tid -= N_ACSROW;
    if (tid < N_W1F) {             // W1 -> bf16 fragment-order [p][kc][nt][lane][8]
        const int n4 = (int)(tid & 31) * 4;
        const int k  = (int)((tid >> 5) % 192);
        const int p  = (int)(tid / 6144);
        const float* W1;
        if (p < 12) { int ai = p / 3, hj = p % 3; W1 = eW1 + (size_t)(hj * NA + ai) * INsz * Dsz; }
        else { int qq = p - 12; int ai = qq >> 1, jj = qq & 1; W1 = iW1 + (size_t)(jj * NA + ai) * INsz * Dsz; }
        float4 f = (k < INsz) ? *(const float4*)(W1 + (size_t)k * Dsz + n4)
                              : (float4){0.f, 0.f, 0.f, 0.f};
        const int kc = k >> 5, q = (k >> 3) & 3, j = k & 7;
        __bf16* dst = (__bf16*)(ws + OFF_W1F);
        const float fv[4] = {f.x, f.y, f.z, f.w};
        #pragma unroll
        for (int i = 0; i < 4; ++i) {
            const int n = n4 + i, nt = n >> 4, m = n & 15;
            dst[((size_t)(p * 6 + kc) * 8 + nt) * 512 + (q * 16 + m) * 8 + j] = (__bf16)fv[i];
        }
        return;
    }
    tid -= N_W1F;
    if (tid < N_ENCWF) {           // encW -> bf16 fragment-order [kc][nt][lane][8]
        const int n4 = (int)(tid & 31) * 4;
        const int k  = (int)(tid >> 5);
        float4 f = *(const float4*)(encW + (size_t)k * Dsz + n4);
        const int kc = k >> 5, q = (k >> 3) & 3, j = k & 7;
        __bf16* dst = (__bf16*)(ws + OFF_ENCWF);
        const float fv[4] = {f.x, f.y, f.z, f.w};
        #pragma unroll
        for (int i = 0; i < 4; ++i) {
            const int n = n4 + i, nt = n >> 4, m = n & 15;
            dst[((size_t)kc * 8 + nt) * 512 + (q * 16 + m) * 8 + j] = (__bf16)fv[i];
        }
        return;
    }
    tid -= N_ENCWF;
    if (tid < N_W2T) {             // W2 -> bf16 transposed [p][c][d]
        int d = (int)(tid & 127);
        int rest = (int)(tid >> 7);
        int c = rest & 15, p = rest >> 4;
        const float* W2;
        if (p < 12) { int ai = p / 3, hj = p % 3; W2 = eW2 + (size_t)(hj * NA + ai) * Dsz * Csz; }
        else { int qq = p - 12; int ai = qq >> 1, jj = qq & 1; W2 = iW2 + (size_t)(jj * NA + ai) * Dsz * Csz; }
        ((__bf16*)(ws + OFF_W2T))[(size_t)p * Csz * Dsz + (size_t)c * Dsz + d] = (__bf16)W2[(size_t)d * Csz + c];
        return;
    }
    tid -= N_W2T;
    if (tid < N_ZERO) ((float*)(ws + OFF_ZERO))[tid] = 0.f;
}

// ---------------- encoder: wave = 16 rows x all 128 cols, coalesced B, no LDS ----------------
__global__ __launch_bounds__(256) void enc_kernel(const float* __restrict__ sv,
                                                  const float* __restrict__ encb,
                                                  char* __restrict__ ws)
{
    const int t = threadIdx.x;
    const int wv = t >> 6, lane = t & 63, m = lane & 15, q = lane >> 4;
    const int R = blockIdx.x * 64 + wv * 16 + m;
    const __bf16* encwf = (const __bf16*)(ws + OFF_ENCWF);
    __bf16* enc = (__bf16*)(ws + OFF_ENC);

    v4f acc[8];
    #pragma unroll
    for (int nt = 0; nt < 8; ++nt) acc[nt] = (v4f){0.f, 0.f, 0.f, 0.f};

    const float* arow = sv + (size_t)R * Ssz + q * 8;
    #pragma unroll
    for (int kc = 0; kc < 8; ++kc) {
        float4 f0 = *(const float4*)(arow + kc * 32);
        float4 f1 = *(const float4*)(arow + kc * 32 + 4);
        v8bf af;
        af[0]=(__bf16)f0.x; af[1]=(__bf16)f0.y; af[2]=(__bf16)f0.z; af[3]=(__bf16)f0.w;
        af[4]=(__bf16)f1.x; af[5]=(__bf16)f1.y; af[6]=(__bf16)f1.z; af[7]=(__bf16)f1.w;
        #pragma unroll
        for (int nt = 0; nt < 8; ++nt) {
            v8bf bf = *(const v8bf*)(encwf + ((size_t)kc * 8 + nt) * 512 + lane * 8);
            acc[nt] = __builtin_amdgcn_mfma_f32_16x16x32_bf16(af, bf, acc[nt], 0, 0, 0);
        }
    }
    const int rbase = blockIdx.x * 64 + wv * 16 + q * 4;
    #pragma unroll
    for (int nt = 0; nt < 8; ++nt) {
        const float bias = encb[nt * 16 + m];
        #pragma unroll
        for (int rg = 0; rg < 4; ++rg) {
            float v = acc[nt][rg] + bias;
            v = v > 0.f ? v : 0.f;
            enc[(size_t)(rbase + rg) * Dsz + nt * 16 + m] = (__bf16)v;
        }
    }
}

// ---------------- critic: 2-D grid (row-inner for XCD affinity), LDS-staged B, 3 waves/SIMD ----------------
__global__ __launch_bounds__(256, 3) void critic_kernel(
    const float* __restrict__ eb1, const float* __restrict__ eb2,
    const float* __restrict__ ib1, const float* __restrict__ ib2,
    const char* __restrict__ ws, float* __restrict__ out)
{
    __shared__ __bf16 w1s[6 * 8 * 512];   // 48 KB: whole B for this p, fragment-order

    const int t = threadIdx.x;
    const int p  = blockIdx.y;
    const int rb = blockIdx.x;
    const int wv = t >> 6, lane = t & 63, m = lane & 15, q = lane >> 4;
    const int rw = rb * 128 + wv * 32;       // this wave's first row

    int ai, hj;
    const float *b1, *b2;
    float* outp;
    if (p < 12) {
        ai = p / 3; hj = p % 3;
        const int wi = hj * NA + ai;
        b1 = eb1 + (size_t)wi * Dsz; b2 = eb2 + (size_t)wi * Csz;
        outp = out + (size_t)(ai * NH + hj) * Bsz;
    } else {
        const int qq = p - 12; ai = qq >> 1; const int jj = qq & 1; hj = jj + 1;
        const int wi = jj * NA + ai;
        b1 = ib1 + (size_t)wi * Dsz; b2 = ib2 + (size_t)wi * Csz;
        outp = out + (size_t)NA * NH * Bsz + (size_t)(ai * NHI + jj) * Bsz;
    }

    const __bf16* acsb = (const __bf16*)(ws + OFF_ACSBF);
    const __bf16* encp = (const __bf16*)(ws + OFF_ENC);
    const __bf16* w1f  = (const __bf16*)(ws + OFF_W1F) + (size_t)p * 6 * 8 * 512;
    const __bf16* w2t  = (const __bf16*)(ws + OFF_W2T) + (size_t)p * Csz * Dsz;
    const unsigned char* amx = (const unsigned char*)(ws + OFF_AMX) + (size_t)(ai * NH + hj) * Bsz + rw;
    const __bf16* zerop = (const __bf16*)(ws + OFF_ZERO);

    // stage whole B block (48 KB) into LDS, one barrier total
    {
        const v8bf* src = (const v8bf*)w1f;
        v8bf* dst = (v8bf*)w1s;
        #pragma unroll
        for (int i = 0; i < 12; ++i)
            dst[i * 256 + t] = src[i * 256 + t];
    }

    const int loo0 = 0 + (0 >= ai), loo1 = 1 + (1 >= ai), loo2 = 2 + (2 >= ai);
    const __bf16* a0p = acsb + (size_t)(loo0 * NH + hj) * Bsz * Csz;
    const __bf16* a1p = acsb + (size_t)(loo1 * NH + hj) * Bsz * Csz;
    const __bf16* a2p = acsb + (size_t)(loo2 * NH + hj) * Bsz * Csz;

    const int R0 = rw + m;
    const __bf16* base[6];
    int strd[6];
    base[0] = (q < 2) ? (a0p + (size_t)R0 * Csz + q * 8) : (a1p + (size_t)R0 * Csz + (q - 2) * 8);
    strd[0] = Csz;
    base[1] = (q < 2) ? (a2p + (size_t)R0 * Csz + q * 8) : (encp + (size_t)R0 * Dsz + (q - 2) * 8);
    strd[1] = (q < 2) ? Csz : Dsz;
    base[2] = encp + (size_t)R0 * Dsz + 16 + q * 8;  strd[2] = Dsz;
    base[3] = encp + (size_t)R0 * Dsz + 48 + q * 8;  strd[3] = Dsz;
    base[4] = encp + (size_t)R0 * Dsz + 80 + q * 8;  strd[4] = Dsz;
    base[5] = (q < 2) ? (encp + (size_t)R0 * Dsz + 112 + q * 8) : zerop;
    strd[5] = (q < 2) ? Dsz : 0;

    v4f acc[2][8];
    #pragma unroll
    for (int i = 0; i < 2; ++i)
        #pragma unroll
        for (int j = 0; j < 8; ++j)
            acc[i][j] = (v4f){0.f, 0.f, 0.f, 0.f};

    __syncthreads();

    #pragma unroll
    for (int kc = 0; kc < 6; ++kc) {
        v8bf af[2];
        #pragma unroll
        for (int mt = 0; mt < 2; ++mt)
            af[mt] = *(const v8bf*)(base[kc] + (size_t)(mt * 16) * strd[kc]);
        #pragma unroll
        for (int nt = 0; nt < 8; ++nt) {
            v8bf bf = *(const v8bf*)&w1s[((size_t)kc * 8 + nt) * 512 + lane * 8];
            acc[0][nt] = __builtin_amdgcn_mfma_f32_16x16x32_bf16(af[0], bf, acc[0][nt], 0, 0, 0);
            acc[1][nt] = __builtin_amdgcn_mfma_f32_16x16x32_bf16(af[1], bf, acc[1][nt], 0, 0, 0);
        }
    }

    // wave-local epilogue: relu(acc+b1) . w2[:,argmax], shfl over the 16 m-lanes, direct store
    float b1v[8];
    #pragma unroll
    for (int nt = 0; nt < 8; ++nt) b1v[nt] = b1[nt * 16 + m];

    #pragma unroll
    for (int mt = 0; mt < 2; ++mt) {
        const int rowb = mt * 16 + q * 4;
        const unsigned int cw = *(const unsigned int*)(amx + rowb);
        #pragma unroll
        for (int rg = 0; rg < 4; ++rg) {
            const int c = (cw >> (8 * rg)) & 255;
            const __bf16* wc = w2t + (size_t)c * Dsz + m;
            float partial = 0.f;
            #pragma unroll
            for (int nt = 0; nt < 8; ++nt) {
                float h = acc[mt][nt][rg] + b1v[nt];
                h = h > 0.f ? h : 0.f;
                partial += h * (float)wc[nt * 16];
            }
            partial += __shfl_xor(partial, 1, 64);
            partial += __shfl_xor(partial, 2, 64);
            partial += __shfl_xor(partial, 4, 64);
            partial += __shfl_xor(partial, 8, 64);
            if (m == 0)
                outp[rw + rowb + rg] = partial + b2[c];
        }
    }
}

extern "C" void kernel_launch(void* const* d_in, const int* in_sizes, int n_in,
                              void* d_out, int out_size, void* d_ws, size_t ws_size,
                              hipStream_t stream) {
    const float* sv   = (const float*)d_in[0];
    const float* acs  = (const float*)d_in[1];
    const float* encW = (const float*)d_in[2];
    const float* encb = (const float*)d_in[3];
    const float* eW1  = (const float*)d_in[4];
    const float* eb1  = (const float*)d_in[5];
    const float* eW2  = (const float*)d_in[6];
    const float* eb2  = (const float*)d_in[7];
    const float* iW1  = (const float*)d_in[8];
    const float* ib1  = (const float*)d_in[9];
    const float* iW2  = (const float*)d_in[10];
    const float* ib2  = (const float*)d_in[11];
    float* out = (float*)d_out;
    char* ws = (char*)d_ws;

    hipLaunchKernelGGL(prep_kernel, dim3((N_PREP + 255) / 256), dim3(256), 0, stream,
                       acs, encW, eW1, iW1, eW2, iW2, ws);
    hipLaunchKernelGGL(enc_kernel, dim3(Bsz / 64), dim3(256), 0, stream, sv, encb, ws);
    hipLaunchKernelGGL(critic_kernel, dim3(Bsz / 128, NP), dim3(256), 0, stream,
                       eb1, eb2, ib1, ib2, ws, out);
}